// Round 9
// baseline (439.503 us; speedup 1.0000x reference)
//
#include <hip/hip_runtime.h>
#include <math.h>

#define N_NODES 50000
#define E_EDGES 1200000
#define H_DIM 64
#define L_LAYERS 2
#define CSLOT 64   // max degree ~56 for Poisson(24) over 50k rows

// prep kernel grid partition
#define NB_SC 4688   // scatter: ceil(E/256)
#define NB_X  3125   // x -> xb (planar bf16): 800000 float4
#define NB_H  3125   // h -> hbI (packed both layers): 800000 float4-pairs
#define NB_PK 512    // weight pack: 131072

typedef __attribute__((ext_vector_type(8))) short bf16x8;
typedef __attribute__((ext_vector_type(4))) float f32x4;

static __device__ __forceinline__ unsigned short f2bf(float f) {
    unsigned u = __float_as_uint(f);
    unsigned r = (u + 0x7FFFu + ((u >> 16) & 1u)) >> 16;
    return (unsigned short)r;
}
static __device__ __forceinline__ float bf2f(unsigned short u) {
    return __uint_as_float(((unsigned)u) << 16);
}
static __device__ __forceinline__ unsigned packbf(float a, float b) {
    return (unsigned)f2bf(a) | ((unsigned)f2bf(b) << 16);
}

// ---------------- fused prep: scatter | x->bf16 | h->packed-bf16x2 | pack ----------------

__global__ void prep_kernel(const int* __restrict__ row, const int* __restrict__ col,
                            const float* __restrict__ ew,
                            int* __restrict__ cnt, unsigned* __restrict__ slots4,
                            const float* __restrict__ x, const float* __restrict__ h,
                            unsigned short* __restrict__ xb, unsigned* __restrict__ hbI,
                            const float* __restrict__ Wx, const float* __restrict__ Wcheb,
                            unsigned short* __restrict__ Wtb) {
    int b = blockIdx.x;
    int tid = threadIdx.x;
    const long NH = (long)N_NODES * H_DIM;
    if (b < NB_SC) {
        int e = b * 256 + tid;
        if (e < E_EDGES) {
            int r = row[e];
            int p = atomicAdd(&cnt[r], 1);
            if (p < CSLOT)
                slots4[(long)r * CSLOT + p] = (unsigned)col[e] | ((unsigned)f2bf(ew[e]) << 16);
        }
    } else if (b < NB_SC + NB_X) {
        int i = (b - NB_SC) * 256 + tid;           // 800000 float4s of x
        float4 v = ((const float4*)x)[i];
        ushort4 o; o.x = f2bf(v.x); o.y = f2bf(v.y); o.z = f2bf(v.z); o.w = f2bf(v.w);
        ((ushort4*)xb)[i] = o;
    } else if (b < NB_SC + NB_X + NB_H) {
        int i = (b - NB_SC - NB_X) * 256 + tid;    // 800000 float4s per layer
        float4 a = ((const float4*)h)[i];
        float4 c = ((const float4*)(h + NH))[i];
        uint4 o;
        o.x = packbf(a.x, c.x); o.y = packbf(a.y, c.y);
        o.z = packbf(a.z, c.z); o.w = packbf(a.w, c.w);
        ((uint4*)hbI)[i] = o;
    } else {
        int i = (b - NB_SC - NB_X - NB_H) * 256 + tid;  // 131072 weight elems
        int k = i & 255;
        int o = (i >> 8) & 63;
        int g = (i >> 14) & 3;
        int l = i >> 16;
        float v;
        if (k < 64) {
            v = Wx[(((l * 4 + g) * 64 + k) * 64) + o];
        } else {
            int kc = (k - 64) >> 6, hh = (k - 64) & 63;
            v = Wcheb[((((l * 4 + g) * 3 + kc) * 64 + hh) * 64) + o];
        }
        Wtb[i] = f2bf(v);
    }
}

// ---------------- degree -> dinv, and pre-scale features: hbIs = dinv[r] * hbI[r] ----------------

__global__ __launch_bounds__(256) void rowsum_scale_kernel(
    const int* __restrict__ cnt, const unsigned* __restrict__ slots4,
    const unsigned* __restrict__ hbI,
    float* __restrict__ dinv, unsigned* __restrict__ hbIs) {
    int lane = threadIdx.x & 63;
    int wv = threadIdx.x >> 6;
    int r = blockIdx.x * 4 + wv;
    if (r >= N_NODES) return;
    int ct = cnt[r]; if (ct > CSLOT) ct = CSLOT;
    unsigned s = slots4[(long)r * CSLOT + lane];
    float w = (lane < ct) ? bf2f((unsigned short)(s >> 16)) : 0.f;
#pragma unroll
    for (int off = 32; off >= 1; off >>= 1) w += __shfl_xor(w, off, 64);
    float dv = w > 0.f ? rsqrtf(w) : 0.f;   // all lanes hold total after butterfly
    if (lane == 0) dinv[r] = dv;
    long o = (long)r * 64 + lane;
    unsigned u = hbI[o];
    float f0 = __uint_as_float(u << 16) * dv;
    float f1 = __uint_as_float(u & 0xFFFF0000u) * dv;
    hbIs[o] = packbf(f0, f1);
}

// ---------------- packed dual-layer SpMV: 1 gather per edge serves both layers ----------------
// pass1 (pass2=0): outU = -dr * sum(ew * ys[col]); outS = dr * outU   (T1 and dinv*T1)
// pass2 (pass2=1): outU = -2*dr * sum(ew * ys[col]) - base            (T2 = 2*L^T1 - h)

__global__ __launch_bounds__(256) void spmv_packed_kernel(
    const int* __restrict__ cnt, const unsigned* __restrict__ slots4,
    const float* __restrict__ dinv,
    const unsigned* __restrict__ ys, const unsigned* __restrict__ base,
    unsigned* __restrict__ outU, unsigned* __restrict__ outS, int pass2) {
    __shared__ int s_col[8][64];
    __shared__ float s_w[8][64];
    int lane = threadIdx.x & 63;
    int wv = threadIdx.x >> 6;
    int rA = blockIdx.x * 8 + wv * 2;
    int rB = rA + 1;
    if (rA >= N_NODES) return;
    bool hasB = (rB < N_NODES);

    int ctA = cnt[rA]; if (ctA > CSLOT) ctA = CSLOT;
    int ctB = 0;
    if (hasB) { ctB = cnt[rB]; if (ctB > CSLOT) ctB = CSLOT; }

    {
        unsigned sA = slots4[(long)rA * CSLOT + lane];
        int cA = (int)(sA & 0xFFFFu); if (cA >= N_NODES) cA = 0;
        s_col[wv * 2][lane] = cA;
        s_w[wv * 2][lane] = (lane < ctA) ? bf2f((unsigned short)(sA >> 16)) : 0.f;
        unsigned sB = hasB ? slots4[(long)rB * CSLOT + lane] : 0u;
        int cB = (int)(sB & 0xFFFFu); if (cB >= N_NODES) cB = 0;
        s_col[wv * 2 + 1][lane] = cB;
        s_w[wv * 2 + 1][lane] = (hasB && lane < ctB) ? bf2f((unsigned short)(sB >> 16)) : 0.f;
    }
    // same-wave LDS producer/consumer: no barrier needed

    int ctA4 = (ctA + 3) & ~3;
    int ctB4 = (ctB + 3) & ~3;
    int mx = ctA4 > ctB4 ? ctA4 : ctB4;

    float aA0 = 0.f, aA1 = 0.f, aB0 = 0.f, aB1 = 0.f;
    for (int j = 0; j < mx; j += 4) {
        if (j < ctA4) {   // wave-uniform
#pragma unroll
            for (int t = 0; t < 4; ++t) {
                int c = s_col[wv * 2][j + t];
                float w = s_w[wv * 2][j + t];
                unsigned u = ys[(long)c * 64 + lane];
                aA0 += w * __uint_as_float(u << 16);
                aA1 += w * __uint_as_float(u & 0xFFFF0000u);
            }
        }
        if (j < ctB4) {   // wave-uniform
#pragma unroll
            for (int t = 0; t < 4; ++t) {
                int c = s_col[wv * 2 + 1][j + t];
                float w = s_w[wv * 2 + 1][j + t];
                unsigned u = ys[(long)c * 64 + lane];
                aB0 += w * __uint_as_float(u << 16);
                aB1 += w * __uint_as_float(u & 0xFFFF0000u);
            }
        }
    }

#pragma unroll
    for (int half = 0; half < 2; ++half) {
        int r = half ? rB : rA;
        if (half && !hasB) break;
        float a0 = half ? aB0 : aA0;
        float a1 = half ? aB1 : aA1;
        long o = (long)r * 64 + lane;
        float dr = dinv[r];
        if (!pass2) {
            float t0 = -dr * a0, t1 = -dr * a1;
            outU[o] = packbf(t0, t1);
            outS[o] = packbf(dr * t0, dr * t1);
        } else {
            unsigned ub = base[o];
            float t0 = -2.f * dr * a0 - __uint_as_float(ub << 16);
            float t1 = -2.f * dr * a1 - __uint_as_float(ub & 0xFFFF0000u);
            outU[o] = packbf(t0, t1);
        }
    }
}

// ---------------- MFMA gate GEMM + fused LSTM pointwise (+ optional fused FC) ----------------
// A sources: inp planar bf16; hbI/tx1I/tx2I packed (extract half `lsel` during staging).

__global__ __launch_bounds__(256) void gates_mfma_kernel(
    const unsigned short* __restrict__ inp_b,
    const unsigned* __restrict__ hbI, const unsigned* __restrict__ tx1I,
    const unsigned* __restrict__ tx2I, int lsel,
    const unsigned short* __restrict__ Wtb_l,
    const float* __restrict__ b_cheb_l, const float* __restrict__ b_gate_l,
    const float* __restrict__ w_peep_l, const float* __restrict__ cl,
    float* __restrict__ h_out, float* __restrict__ c_out,
    unsigned short* __restrict__ hob, int write_hob,
    const float* __restrict__ fcw, const float* __restrict__ fcb,
    float* __restrict__ fc_out, int do_fc) {
    __shared__ __align__(16) char smem[64 * 264 * 2];
    unsigned short (*s_A)[264] = (unsigned short (*)[264])smem;
    float (*s_acc)[257] = (float (*)[257])smem;

    int tid = threadIdx.x;
    int nb = blockIdx.x * 64;

    // src0: planar bf16 input, 16B/thread-iter
#pragma unroll
    for (int it = 0; it < 2; ++it) {
        int idx = tid + it * 256;   // 0..511
        int nl = idx >> 3;
        int off = (idx & 7) * 8;
        int n = nb + nl;
        bf16x8 v = (bf16x8)0;
        if (n < N_NODES) v = *(const bf16x8*)&inp_b[(long)n * 64 + off];
        *(bf16x8*)&s_A[nl][off] = v;
    }
    // srcs 1..3: packed u32 per channel; extract half lsel
#pragma unroll
    for (int src = 0; src < 3; ++src) {
        const unsigned* P = (src == 0) ? hbI : (src == 1) ? tx1I : tx2I;
#pragma unroll
        for (int it = 0; it < 4; ++it) {
            int idx = tid + it * 256;   // 0..1023
            int nl = idx >> 4;
            int q = (idx & 15) * 4;
            int n = nb + nl;
            ushort4 o4 = make_ushort4(0, 0, 0, 0);
            if (n < N_NODES) {
                uint4 u = *(const uint4*)&P[(long)n * 64 + q];
                if (lsel) {
                    o4.x = (unsigned short)(u.x >> 16); o4.y = (unsigned short)(u.y >> 16);
                    o4.z = (unsigned short)(u.z >> 16); o4.w = (unsigned short)(u.w >> 16);
                } else {
                    o4.x = (unsigned short)u.x; o4.y = (unsigned short)u.y;
                    o4.z = (unsigned short)u.z; o4.w = (unsigned short)u.w;
                }
            }
            *(ushort4*)&s_A[nl][(src + 1) * 64 + q] = o4;
        }
    }
    __syncthreads();

    int lane = tid & 63;
    int wv = tid >> 6;
    int quad = lane >> 4;
    int l16 = lane & 15;
    const unsigned short* Wg = Wtb_l + wv * 64 * 256;

    float fcv = 0.f, fcb0 = 0.f;
    if (do_fc) { fcv = fcw[lane]; fcb0 = fcb[0]; }

    f32x4 acc[4][4];
#pragma unroll
    for (int mt = 0; mt < 4; ++mt)
#pragma unroll
        for (int nt = 0; nt < 4; ++nt) acc[mt][nt] = (f32x4)(0.f);

    for (int ks = 0; ks < 8; ++ks) {
        int k0 = ks * 32 + quad * 8;
        bf16x8 a[4], b[4];
#pragma unroll
        for (int mt = 0; mt < 4; ++mt)
            a[mt] = *(const bf16x8*)&s_A[mt * 16 + l16][k0];
#pragma unroll
        for (int nt = 0; nt < 4; ++nt)
            b[nt] = *(const bf16x8*)&Wg[(nt * 16 + l16) * 256 + k0];
#pragma unroll
        for (int mt = 0; mt < 4; ++mt)
#pragma unroll
            for (int nt = 0; nt < 4; ++nt)
                acc[mt][nt] = __builtin_amdgcn_mfma_f32_16x16x32_bf16(a[mt], b[nt], acc[mt][nt], 0, 0, 0);
    }

    for (int mt = 0; mt < 4; ++mt) {
        __syncthreads();
#pragma unroll
        for (int nt = 0; nt < 4; ++nt)
#pragma unroll
            for (int r = 0; r < 4; ++r)
                s_acc[quad * 4 + r][wv * 64 + nt * 16 + l16] = acc[mt][nt][r];
        __syncthreads();
#pragma unroll
        for (int rep = 0; rep < 4; ++rep) {
            int idx = tid + rep * 256;
            int o = idx & 63;      // == lane
            int nl = idx >> 6;     // wave-uniform
            int n = nb + mt * 16 + nl;
            if (n < N_NODES) {
                float cv = cl[(long)n * 64 + o];
                float gi = s_acc[nl][0 * 64 + o] + b_cheb_l[0 * 64 + o] + b_gate_l[0 * 64 + o] + w_peep_l[0 * 64 + o] * cv;
                float gf = s_acc[nl][1 * 64 + o] + b_cheb_l[1 * 64 + o] + b_gate_l[1 * 64 + o] + w_peep_l[1 * 64 + o] * cv;
                float gt = s_acc[nl][2 * 64 + o] + b_cheb_l[2 * 64 + o] + b_gate_l[2 * 64 + o];
                float go = s_acc[nl][3 * 64 + o] + b_cheb_l[3 * 64 + o] + b_gate_l[3 * 64 + o];
                float ig = 1.f / (1.f + __expf(-gi));
                float fg = 1.f / (1.f + __expf(-gf));
                float tg = tanhf(gt);
                float ct = fg * cv + ig * tg;
                float og = 1.f / (1.f + __expf(-(go + w_peep_l[2 * 64 + o] * ct)));
                float ht = og * tanhf(ct);
                h_out[(long)n * 64 + o] = ht;
                c_out[(long)n * 64 + o] = ct;
                if (write_hob) hob[(long)n * 64 + o] = f2bf(ht);
                if (do_fc) {
                    float v = ht * fcv;
#pragma unroll
                    for (int off = 32; off >= 1; off >>= 1) v += __shfl_xor(v, off, 64);
                    if (lane == 0) fc_out[n] = v + fcb0;
                }
            }
        }
    }
}

extern "C" void kernel_launch(void* const* d_in, const int* in_sizes, int n_in,
                              void* d_out, int out_size, void* d_ws, size_t ws_size,
                              hipStream_t stream) {
    const float* x      = (const float*)d_in[0];
    const int*   ei     = (const int*)d_in[1];
    const float* ew     = (const float*)d_in[2];
    const float* h      = (const float*)d_in[3];
    const float* c      = (const float*)d_in[4];
    const float* Wx     = (const float*)d_in[5];
    const float* Wcheb  = (const float*)d_in[6];
    const float* b_cheb = (const float*)d_in[7];
    const float* w_peep = (const float*)d_in[8];
    const float* b_gate = (const float*)d_in[9];
    const float* fc_w   = (const float*)d_in[10];
    const float* fc_b   = (const float*)d_in[11];
    float* out = (float*)d_out;

    const int* row = ei;
    const int* col = ei + E_EDGES;
    const long NH = (long)N_NODES * H_DIM;

    // workspace (4B units): cnt | dinv | slots4 | hbI | hbIs(=tx2I) | tx1I | tx1Is | xb(bf16) | Wtb(bf16)
    float* W = (float*)d_ws;
    int*      cnt    = (int*)W;                            // 50000
    float*    dinv   = W + 50000;                          // 50000
    unsigned* slots4 = (unsigned*)(W + 100000);            // 3.2M = 12.8 MB
    unsigned* hbI    = slots4 + (long)N_NODES * CSLOT;     // 3.2M
    unsigned* hbIs   = hbI + NH;                           // 3.2M (dead after pass1 -> reused as tx2I)
    unsigned* tx1I   = hbIs + NH;                          // 3.2M
    unsigned* tx1Is  = tx1I + NH;                          // 3.2M
    unsigned short* xb  = (unsigned short*)(tx1Is + NH);   // 3.2M ushort (aliased as hob)
    unsigned short* Wtb = xb + NH;                         // 131072
    unsigned* tx2I = hbIs;                                 // alias
    // total ~71 MB

    hipMemsetAsync(cnt, 0, N_NODES * sizeof(int), stream);
    prep_kernel<<<NB_SC + NB_X + NB_H + NB_PK, 256, 0, stream>>>(
        row, col, ew, cnt, slots4, x, h, xb, hbI, Wx, Wcheb, Wtb);
    rowsum_scale_kernel<<<(N_NODES + 3) / 4, 256, 0, stream>>>(cnt, slots4, hbI, dinv, hbIs);

    // pass1: T1 = L^h (both layers packed); also scaled T1 for pass2's gather
    spmv_packed_kernel<<<(N_NODES + 7) / 8, 256, 0, stream>>>(
        cnt, slots4, dinv, hbIs, (const unsigned*)nullptr, tx1I, tx1Is, 0);
    // pass2: T2 = 2 L^T1 - h (both layers packed); writes over dead hbIs
    spmv_packed_kernel<<<(N_NODES + 7) / 8, 256, 0, stream>>>(
        cnt, slots4, dinv, tx1Is, hbI, tx2I, (unsigned*)nullptr, 1);

    float* h_out_base = out + N_NODES;
    float* c_out_base = out + N_NODES + (long)L_LAYERS * NH;

    // layer 0 (hob aliases xb: blocks read their xb rows in staging before epilogue writes)
    gates_mfma_kernel<<<(N_NODES + 63) / 64, 256, 0, stream>>>(
        xb, hbI, tx1I, tx2I, 0, Wtb,
        b_cheb, b_gate, w_peep, c,
        h_out_base, c_out_base, xb, 1,
        fc_w, fc_b, out, 0);
    // layer 1 (+ fused FC head)
    gates_mfma_kernel<<<(N_NODES + 63) / 64, 256, 0, stream>>>(
        xb, hbI, tx1I, tx2I, 1, Wtb + (long)4 * 64 * 256,
        b_cheb + 4 * 64, b_gate + 4 * 64, w_peep + 3 * 64, c + NH,
        h_out_base + NH, c_out_base + NH, xb, 0,
        fc_w, fc_b, out, 1);
}

// Round 10
// 394.733 us; speedup vs baseline: 1.1134x; 1.1134x over previous
//
#include <hip/hip_runtime.h>
#include <math.h>

#define N_NODES 50000
#define E_EDGES 1200000
#define H_DIM 64
#define L_LAYERS 2
#define CSLOT 64   // max degree ~56 for Poisson(24) over 50k rows
#define FP8_SC 16.0f
#define FP8_ISC 0.0625f

// prep kernel grid partition
#define NB_SC 4688   // scatter: ceil(E/256)
#define NB_X  3125   // x -> xb (planar bf16): 800000 float4
#define NB_H  3125   // h -> hbI (packed both layers): 800000 float4-pairs
#define NB_PK 512    // weight pack: 131072

typedef __attribute__((ext_vector_type(8))) short bf16x8;
typedef __attribute__((ext_vector_type(4))) float f32x4;

static __device__ __forceinline__ unsigned short f2bf(float f) {
    unsigned u = __float_as_uint(f);
    unsigned r = (u + 0x7FFFu + ((u >> 16) & 1u)) >> 16;
    return (unsigned short)r;
}
static __device__ __forceinline__ float bf2f(unsigned short u) {
    return __uint_as_float(((unsigned)u) << 16);
}
static __device__ __forceinline__ unsigned packbf(float a, float b) {
    return (unsigned)f2bf(a) | ((unsigned)f2bf(b) << 16);
}
// fp8 e4m3 (OCP) pack/unpack via gfx950 HW converts
static __device__ __forceinline__ unsigned short pk8(float a, float b) {
    int v = __builtin_amdgcn_cvt_pk_fp8_f32(a, b, 0, false);
    return (unsigned short)(v & 0xFFFF);
}
static __device__ __forceinline__ float f8lo(unsigned u) {
    return __builtin_amdgcn_cvt_f32_fp8((int)u, 0);
}
static __device__ __forceinline__ float f8hi(unsigned u) {
    return __builtin_amdgcn_cvt_f32_fp8((int)u, 1);
}

// ---------------- fused prep: scatter | x->bf16 | h->packed-bf16x2 | pack ----------------

__global__ void prep_kernel(const int* __restrict__ row, const int* __restrict__ col,
                            const float* __restrict__ ew,
                            int* __restrict__ cnt, unsigned* __restrict__ slots4,
                            const float* __restrict__ x, const float* __restrict__ h,
                            unsigned short* __restrict__ xb, unsigned* __restrict__ hbI,
                            const float* __restrict__ Wx, const float* __restrict__ Wcheb,
                            unsigned short* __restrict__ Wtb) {
    int b = blockIdx.x;
    int tid = threadIdx.x;
    const long NH = (long)N_NODES * H_DIM;
    if (b < NB_SC) {
        int e = b * 256 + tid;
        if (e < E_EDGES) {
            int r = row[e];
            int p = atomicAdd(&cnt[r], 1);
            if (p < CSLOT)
                slots4[(long)r * CSLOT + p] = (unsigned)col[e] | ((unsigned)f2bf(ew[e]) << 16);
        }
    } else if (b < NB_SC + NB_X) {
        int i = (b - NB_SC) * 256 + tid;
        float4 v = ((const float4*)x)[i];
        ushort4 o; o.x = f2bf(v.x); o.y = f2bf(v.y); o.z = f2bf(v.z); o.w = f2bf(v.w);
        ((ushort4*)xb)[i] = o;
    } else if (b < NB_SC + NB_X + NB_H) {
        int i = (b - NB_SC - NB_X) * 256 + tid;
        float4 a = ((const float4*)h)[i];
        float4 c = ((const float4*)(h + NH))[i];
        uint4 o;
        o.x = packbf(a.x, c.x); o.y = packbf(a.y, c.y);
        o.z = packbf(a.z, c.z); o.w = packbf(a.w, c.w);
        ((uint4*)hbI)[i] = o;
    } else {
        int i = (b - NB_SC - NB_X - NB_H) * 256 + tid;
        int k = i & 255;
        int o = (i >> 8) & 63;
        int g = (i >> 14) & 3;
        int l = i >> 16;
        float v;
        if (k < 64) {
            v = Wx[(((l * 4 + g) * 64 + k) * 64) + o];
        } else {
            int kc = (k - 64) >> 6, hh = (k - 64) & 63;
            v = Wcheb[((((l * 4 + g) * 3 + kc) * 64 + hh) * 64) + o];
        }
        Wtb[i] = f2bf(v);
    }
}

// ---------------- degree -> dinv; hb8s = e4m3(SC * dinv[r] * h[r]) both layers ----------------

__global__ __launch_bounds__(256) void rowsum_scale_kernel(
    const int* __restrict__ cnt, const unsigned* __restrict__ slots4,
    const unsigned* __restrict__ hbI,
    float* __restrict__ dinv, unsigned short* __restrict__ hb8s) {
    int lane = threadIdx.x & 63;
    int wv = threadIdx.x >> 6;
    int r = blockIdx.x * 4 + wv;
    if (r >= N_NODES) return;
    int ct = cnt[r]; if (ct > CSLOT) ct = CSLOT;
    unsigned s = slots4[(long)r * CSLOT + lane];
    float w = (lane < ct) ? bf2f((unsigned short)(s >> 16)) : 0.f;
#pragma unroll
    for (int off = 32; off >= 1; off >>= 1) w += __shfl_xor(w, off, 64);
    float dv = w > 0.f ? rsqrtf(w) : 0.f;
    if (lane == 0) dinv[r] = dv;
    long o = (long)r * 64 + lane;
    unsigned u = hbI[o];
    float f0 = __uint_as_float(u << 16) * dv * FP8_SC;
    float f1 = __uint_as_float(u & 0xFFFF0000u) * dv * FP8_SC;
    hb8s[o] = pk8(f0, f1);
}

// ---------------- fp8-gather dual-layer SpMV (1 row/wave, 128B/edge) ----------------
// y8[c] = e4m3(SC * dinv[c] * F[c]);  sum = SC * sum(w * dinv*F)
// pass1: T1 = -dr/SC * sum ; write bf16x2 T1 and e4m3(SC*dr*T1) for pass2
// pass2: T2 = -2*dr/SC * sum - h ; write bf16x2 T2

__global__ __launch_bounds__(256) void spmv_f8_kernel(
    const int* __restrict__ cnt, const unsigned* __restrict__ slots4,
    const float* __restrict__ dinv,
    const unsigned short* __restrict__ y8, const unsigned* __restrict__ base,
    unsigned* __restrict__ outU, unsigned short* __restrict__ outS, int pass2) {
    __shared__ int s_col[4][64];
    __shared__ float s_w[4][64];
    int lane = threadIdx.x & 63;
    int wv = threadIdx.x >> 6;
    int r = blockIdx.x * 4 + wv;
    if (r >= N_NODES) return;
    int ct = cnt[r]; if (ct > CSLOT) ct = CSLOT;

    unsigned s = slots4[(long)r * CSLOT + lane];
    int cc = (int)(s & 0xFFFFu); if (cc >= N_NODES) cc = 0;
    s_col[wv][lane] = cc;
    s_w[wv][lane] = (lane < ct) ? bf2f((unsigned short)(s >> 16)) : 0.f;
    // same-wave LDS producer/consumer: no barrier needed

    int ct8 = (ct + 7) & ~7;   // zero-padded (w=0, col clamped)
    float a0 = 0.f, a1 = 0.f;
    for (int j = 0; j < ct8; j += 8) {
        unsigned u[8]; float w[8];
#pragma unroll
        for (int t = 0; t < 8; ++t) {
            int c = s_col[wv][j + t];
            w[t] = s_w[wv][j + t];
            u[t] = y8[(long)c * 64 + lane];
        }
#pragma unroll
        for (int t = 0; t < 8; ++t) {
            a0 += w[t] * f8lo(u[t]);
            a1 += w[t] * f8hi(u[t]);
        }
    }

    long o = (long)r * 64 + lane;
    float dr = dinv[r];
    if (!pass2) {
        float t0 = -dr * FP8_ISC * a0;
        float t1 = -dr * FP8_ISC * a1;
        outU[o] = packbf(t0, t1);
        outS[o] = pk8(FP8_SC * dr * t0, FP8_SC * dr * t1);
    } else {
        unsigned ub = base[o];
        float t0 = -2.f * dr * FP8_ISC * a0 - __uint_as_float(ub << 16);
        float t1 = -2.f * dr * FP8_ISC * a1 - __uint_as_float(ub & 0xFFFF0000u);
        outU[o] = packbf(t0, t1);
    }
}

// ---------------- MFMA gate GEMM + fused LSTM pointwise (+ optional fused FC) ----------------

__global__ __launch_bounds__(256) void gates_mfma_kernel(
    const unsigned short* __restrict__ inp_b,
    const unsigned* __restrict__ hbI, const unsigned* __restrict__ tx1I,
    const unsigned* __restrict__ tx2I, int lsel,
    const unsigned short* __restrict__ Wtb_l,
    const float* __restrict__ b_cheb_l, const float* __restrict__ b_gate_l,
    const float* __restrict__ w_peep_l, const float* __restrict__ cl,
    float* __restrict__ h_out, float* __restrict__ c_out,
    unsigned short* __restrict__ hob, int write_hob,
    const float* __restrict__ fcw, const float* __restrict__ fcb,
    float* __restrict__ fc_out, int do_fc) {
    __shared__ __align__(16) char smem[64 * 264 * 2];
    unsigned short (*s_A)[264] = (unsigned short (*)[264])smem;
    float (*s_acc)[257] = (float (*)[257])smem;

    int tid = threadIdx.x;
    int nb = blockIdx.x * 64;

#pragma unroll
    for (int it = 0; it < 2; ++it) {
        int idx = tid + it * 256;
        int nl = idx >> 3;
        int off = (idx & 7) * 8;
        int n = nb + nl;
        bf16x8 v = (bf16x8)0;
        if (n < N_NODES) v = *(const bf16x8*)&inp_b[(long)n * 64 + off];
        *(bf16x8*)&s_A[nl][off] = v;
    }
#pragma unroll
    for (int src = 0; src < 3; ++src) {
        const unsigned* P = (src == 0) ? hbI : (src == 1) ? tx1I : tx2I;
#pragma unroll
        for (int it = 0; it < 4; ++it) {
            int idx = tid + it * 256;
            int nl = idx >> 4;
            int q = (idx & 15) * 4;
            int n = nb + nl;
            ushort4 o4 = make_ushort4(0, 0, 0, 0);
            if (n < N_NODES) {
                uint4 u = *(const uint4*)&P[(long)n * 64 + q];
                if (lsel) {
                    o4.x = (unsigned short)(u.x >> 16); o4.y = (unsigned short)(u.y >> 16);
                    o4.z = (unsigned short)(u.z >> 16); o4.w = (unsigned short)(u.w >> 16);
                } else {
                    o4.x = (unsigned short)u.x; o4.y = (unsigned short)u.y;
                    o4.z = (unsigned short)u.z; o4.w = (unsigned short)u.w;
                }
            }
            *(ushort4*)&s_A[nl][(src + 1) * 64 + q] = o4;
        }
    }
    __syncthreads();

    int lane = tid & 63;
    int wv = tid >> 6;
    int quad = lane >> 4;
    int l16 = lane & 15;
    const unsigned short* Wg = Wtb_l + wv * 64 * 256;

    float fcv = 0.f, fcb0 = 0.f;
    if (do_fc) { fcv = fcw[lane]; fcb0 = fcb[0]; }

    f32x4 acc[4][4];
#pragma unroll
    for (int mt = 0; mt < 4; ++mt)
#pragma unroll
        for (int nt = 0; nt < 4; ++nt) acc[mt][nt] = (f32x4)(0.f);

    for (int ks = 0; ks < 8; ++ks) {
        int k0 = ks * 32 + quad * 8;
        bf16x8 a[4], b[4];
#pragma unroll
        for (int mt = 0; mt < 4; ++mt)
            a[mt] = *(const bf16x8*)&s_A[mt * 16 + l16][k0];
#pragma unroll
        for (int nt = 0; nt < 4; ++nt)
            b[nt] = *(const bf16x8*)&Wg[(nt * 16 + l16) * 256 + k0];
#pragma unroll
        for (int mt = 0; mt < 4; ++mt)
#pragma unroll
            for (int nt = 0; nt < 4; ++nt)
                acc[mt][nt] = __builtin_amdgcn_mfma_f32_16x16x32_bf16(a[mt], b[nt], acc[mt][nt], 0, 0, 0);
    }

    for (int mt = 0; mt < 4; ++mt) {
        __syncthreads();
#pragma unroll
        for (int nt = 0; nt < 4; ++nt)
#pragma unroll
            for (int r = 0; r < 4; ++r)
                s_acc[quad * 4 + r][wv * 64 + nt * 16 + l16] = acc[mt][nt][r];
        __syncthreads();
#pragma unroll
        for (int rep = 0; rep < 4; ++rep) {
            int idx = tid + rep * 256;
            int o = idx & 63;      // == lane
            int nl = idx >> 6;     // wave-uniform
            int n = nb + mt * 16 + nl;
            if (n < N_NODES) {
                float cv = cl[(long)n * 64 + o];
                float gi = s_acc[nl][0 * 64 + o] + b_cheb_l[0 * 64 + o] + b_gate_l[0 * 64 + o] + w_peep_l[0 * 64 + o] * cv;
                float gf = s_acc[nl][1 * 64 + o] + b_cheb_l[1 * 64 + o] + b_gate_l[1 * 64 + o] + w_peep_l[1 * 64 + o] * cv;
                float gt = s_acc[nl][2 * 64 + o] + b_cheb_l[2 * 64 + o] + b_gate_l[2 * 64 + o];
                float go = s_acc[nl][3 * 64 + o] + b_cheb_l[3 * 64 + o] + b_gate_l[3 * 64 + o];
                float ig = 1.f / (1.f + __expf(-gi));
                float fg = 1.f / (1.f + __expf(-gf));
                float tg = tanhf(gt);
                float ct = fg * cv + ig * tg;
                float og = 1.f / (1.f + __expf(-(go + w_peep_l[2 * 64 + o] * ct)));
                float ht = og * tanhf(ct);
                h_out[(long)n * 64 + o] = ht;
                c_out[(long)n * 64 + o] = ct;
                if (write_hob) hob[(long)n * 64 + o] = f2bf(ht);
                if (do_fc) {
                    float v = ht * fcv;
#pragma unroll
                    for (int off = 32; off >= 1; off >>= 1) v += __shfl_xor(v, off, 64);
                    if (lane == 0) fc_out[n] = v + fcb0;
                }
            }
        }
    }
}

extern "C" void kernel_launch(void* const* d_in, const int* in_sizes, int n_in,
                              void* d_out, int out_size, void* d_ws, size_t ws_size,
                              hipStream_t stream) {
    const float* x      = (const float*)d_in[0];
    const int*   ei     = (const int*)d_in[1];
    const float* ew     = (const float*)d_in[2];
    const float* h      = (const float*)d_in[3];
    const float* c      = (const float*)d_in[4];
    const float* Wx     = (const float*)d_in[5];
    const float* Wcheb  = (const float*)d_in[6];
    const float* b_cheb = (const float*)d_in[7];
    const float* w_peep = (const float*)d_in[8];
    const float* b_gate = (const float*)d_in[9];
    const float* fc_w   = (const float*)d_in[10];
    const float* fc_b   = (const float*)d_in[11];
    float* out = (float*)d_out;

    const int* row = ei;
    const int* col = ei + E_EDGES;
    const long NH = (long)N_NODES * H_DIM;

    // workspace (4B units)
    float* W = (float*)d_ws;
    int*      cnt    = (int*)W;                            // 50000
    float*    dinv   = W + 50000;                          // 50000
    unsigned* slots4 = (unsigned*)(W + 100000);            // 3.2M u32
    unsigned* hbI    = slots4 + (long)N_NODES * CSLOT;     // 3.2M u32
    unsigned* tx1I   = hbI + NH;                           // 3.2M u32
    unsigned* tx2I   = tx1I + NH;                          // 3.2M u32
    unsigned short* hb8s = (unsigned short*)(tx2I + NH);   // 3.2M u16
    unsigned short* t18s = hb8s + NH;                      // 3.2M u16
    unsigned short* xb   = t18s + NH;                      // 3.2M u16 (aliased as hob)
    unsigned short* Wtb  = xb + NH;                        // 131072 u16
    // total ~71 MB

    hipMemsetAsync(cnt, 0, N_NODES * sizeof(int), stream);
    prep_kernel<<<NB_SC + NB_X + NB_H + NB_PK, 256, 0, stream>>>(
        row, col, ew, cnt, slots4, x, h, xb, hbI, Wx, Wcheb, Wtb);
    rowsum_scale_kernel<<<(N_NODES + 3) / 4, 256, 0, stream>>>(cnt, slots4, hbI, dinv, hb8s);

    // pass1: T1 (bf16x2) + scaled-fp8 T1 for pass2
    spmv_f8_kernel<<<(N_NODES + 3) / 4, 256, 0, stream>>>(
        cnt, slots4, dinv, hb8s, (const unsigned*)nullptr, tx1I, t18s, 0);
    // pass2: T2 = 2 L^ T1 - h (bf16x2)
    spmv_f8_kernel<<<(N_NODES + 3) / 4, 256, 0, stream>>>(
        cnt, slots4, dinv, t18s, hbI, tx2I, (unsigned short*)nullptr, 1);

    float* h_out_base = out + N_NODES;
    float* c_out_base = out + N_NODES + (long)L_LAYERS * NH;

    // layer 0 (hob aliases xb: blocks read their xb rows in staging before epilogue writes)
    gates_mfma_kernel<<<(N_NODES + 63) / 64, 256, 0, stream>>>(
        xb, hbI, tx1I, tx2I, 0, Wtb,
        b_cheb, b_gate, w_peep, c,
        h_out_base, c_out_base, xb, 1,
        fc_w, fc_b, out, 0);
    // layer 1 (+ fused FC head)
    gates_mfma_kernel<<<(N_NODES + 63) / 64, 256, 0, stream>>>(
        xb, hbI, tx1I, tx2I, 1, Wtb + (long)4 * 64 * 256,
        b_cheb + 4 * 64, b_gate + 4 * 64, w_peep + 3 * 64, c + NH,
        h_out_base + NH, c_out_base + NH, xb, 0,
        fc_w, fc_b, out, 1);
}